// Round 1
// baseline (317.898 us; speedup 1.0000x reference)
//
#include <hip/hip_runtime.h>
#include <hip/hip_cooperative_groups.h>

namespace cg = cooperative_groups;

#define B_N 256
#define IC_N 1152
#define J_N 10
#define D_N 16

typedef __attribute__((ext_vector_type(8))) short short8;
typedef __attribute__((ext_vector_type(4))) float floatx4;

union u4s8 { uint4 u; short8 s; };

__device__ __forceinline__ float bf_lo(unsigned int u){
  union { unsigned int i; float f; } c; c.i = u << 16; return c.f;
}
__device__ __forceinline__ float bf_hi(unsigned int u){
  union { unsigned int i; float f; } c; c.i = u & 0xffff0000u; return c.f;
}
__device__ __forceinline__ unsigned int rne16(float f){
  union { float ff; unsigned int i; } c; c.ff = f;
  return (c.i + 0x7FFFu + ((c.i >> 16) & 1u)) >> 16;
}
__device__ __forceinline__ unsigned int pack_rne(float lo, float hi){
  return rne16(lo) | (rne16(hi) << 16);
}
__device__ __forceinline__ unsigned int pack_trunc(float lo, float hi){
  union { float f; unsigned int u; } a, b; a.f = lo; b.f = hi;
  return __builtin_amdgcn_perm(b.u, a.u, 0x07060302u);
}

// Fully fused: prep + 3x(pass, squash) in ONE cooperative launch.
// Kernel boundaries (6 of them, ~8-10us each in the graph) become
// cg grid syncs (~1-3us each). All per-phase bodies are verbatim
// transplants of the verified 7-kernel version; only the block->work
// mappings changed (strided virtual-block loops so any grid size works).
__global__ __launch_bounds__(640, 5) void caps_fused(
    const float* __restrict__ x, const float* __restrict__ W,
    uint4* __restrict__ wsf, uint4* __restrict__ wcc2,
    float* __restrict__ s_part, float* __restrict__ vsum,
    unsigned int* __restrict__ vsbf_u, float* __restrict__ out)
{
  cg::grid_group grid = cg::this_grid();
  const int tid  = threadIdx.x;
  const int blk  = blockIdx.x;
  const int nblk = gridDim.x;

  __shared__ unsigned int lw2[2][1024];     // prep W staging (2 virtual blocks)
  __shared__ float ccl[10 * 16 * 17];       // 10.6 KB
  __shared__ unsigned int xt[16 * 17 * 4];  // 4.3 KB
  const uint4* xtq = (const uint4*)xt;

  // ---------------- prep: zero vsum ----------------
  for (int g = blk * 640 + tid; g < B_N * J_N * D_N; g += nblk * 640)
    vsum[g] = 0.f;

  // ---------------- prep: W -> wsf + wcc2 (layouts verified R5..R13) ------
  {
    const int grp = tid >> 8;               // 0,1 active; 2 idle
    const int p   = tid & 255;
    for (int base = 0; base < 720; base += nblk * 2) {
      const int pvb = base + blk * 2 + grp;
      const bool act = (grp < 2) && (pvb < 720);
      unsigned int* lw = lw2[grp & 1];
      const int j = pvb / 72, itile = pvb % 72;
      if (act) {
        const float4* Wt = (const float4*)(W + ((size_t)(j * IC_N + itile * 16) << 7));
        #pragma unroll
        for (int h = 0; h < 2; ++h) {
          const float4 f = Wt[h * 256 + p];
          lw[(h * 256 + p) * 2]     = pack_rne(f.x, f.y);
          lw[(h * 256 + p) * 2 + 1] = pack_rne(f.z, f.w);
        }
      }
      __syncthreads();
      if (act) {
        {  // wsf emit
          const int ktl = p >> 6, ln = p & 63;
          const int fb = (ktl * 4 + (ln >> 4)) * 64 + (ln & 15) * 4;
          uint4 q;
          q.x = lw[fb]; q.y = lw[fb + 1]; q.z = lw[fb + 2]; q.w = lw[fb + 3];
          wsf[((size_t)j * 288 + itile * 4 + ktl) * 64 + ln] = q;
        }
        {  // wcc2 emit
          const int e = p >> 5, lane2 = p & 31;
          const int il = lane2 & 15, dbase = (lane2 >> 4) * 8;
          unsigned short h[8];
          #pragma unroll
          for (int k = 0; k < 8; ++k) {
            const unsigned int u = lw[il * 64 + (dbase + k) * 4 + (e >> 1)];
            h[k] = (e & 1) ? (unsigned short)(u >> 16) : (unsigned short)(u & 0xffffu);
          }
          uint4 q;
          q.x = h[0] | ((unsigned int)h[1] << 16);
          q.y = h[2] | ((unsigned int)h[3] << 16);
          q.z = h[4] | ((unsigned int)h[5] << 16);
          q.w = h[6] | ((unsigned int)h[7] << 16);
          wcc2[(((size_t)j * 8 + e) * 72 + itile) * 32 + lane2] = q;
        }
      }
      __syncthreads();
    }
  }

  grid.sync();   // wsf/wcc2/vsum visible to all XCDs

  const int wave = tid >> 6;                // = j
  const int lane = tid & 63;
  const int quad = lane >> 4;
  const int col  = lane & 15;

  for (int round = 0; round < 3; ++round) {
    // ---------------- pass: virtual grid (16 btiles x 72 ichunks) --------
    for (int vbid = blk; vbid < 16 * 72; vbid += nblk) {
      const int bx = vbid & 15;             // btile  (was blockIdx.x)
      const int by = vbid >> 4;             // ichunk (was blockIdx.y)
      const int b0 = bx << 4;
      const int i0 = by << 4;

      __syncthreads();                      // guard xt/ccl reuse across vbid
      if (tid < 512) {                      // stage x tile -> LDS
        const int b = tid >> 5, j4 = tid & 31;
        const int i = j4 >> 1, half = j4 & 1;
        const float4 v = ((const float4*)(x + ((size_t)((b0 + b) * IC_N + i0 + i) << 3)))[half];
        const int idx = ((i * 17 + b) << 2) + (half << 1);
        xt[idx]     = pack_rne(v.x, v.y);
        xt[idx + 1] = pack_rne(v.z, v.w);
      }
      __syncthreads();

      if (round > 0) {                      // phase A: cc update + softmax
        short8 av = {0,0,0,0,0,0,0,0};
        if (quad < 2)
          av = *(const short8*)((const uint4*)vsbf_u +
                                ((size_t)(b0 + col) * J_N + wave) * 2 + quad);
        uint4 bvq[8];
        #pragma unroll
        for (int e = 0; e < 8; ++e) {
          uint4 q = {0u, 0u, 0u, 0u};
          if (lane < 32)
            q = wcc2[(((size_t)wave * 8 + e) * 72 + by) * 32 + lane];
          bvq[e] = q;
        }
        uint4 xr[4];
        #pragma unroll
        for (int r = 0; r < 4; ++r)
          xr[r] = xtq[col * 17 + quad * 4 + r];
        floatx4 cc4 = {0.f, 0.f, 0.f, 0.f};
        #pragma unroll
        for (int e = 0; e < 8; ++e) {
          u4s8 bv; bv.u = bvq[e];
          floatx4 tf = {0.f, 0.f, 0.f, 0.f};
          tf = __builtin_amdgcn_mfma_f32_16x16x32_bf16(av, bv.s, tf, 0, 0, 0);
          #pragma unroll
          for (int r = 0; r < 4; ++r) {
            const unsigned int u = ((const unsigned int*)&xr[r])[e >> 1];
            const float xe = (e & 1) ? bf_hi(u) : bf_lo(u);
            cc4[r] += tf[r] * xe;
          }
        }
        #pragma unroll
        for (int r = 0; r < 4; ++r)
          ccl[(wave * 16 + col) * 17 + quad * 4 + r] = cc4[r];
        __syncthreads();
        if (tid < 256) {                    // softmax over j per (i,b)
          const int i = tid >> 4, b = tid & 15;
          float cc[10];
          #pragma unroll
          for (int j = 0; j < 10; ++j) cc[j] = ccl[(j * 16 + i) * 17 + b];
          float m = cc[0];
          #pragma unroll
          for (int j = 1; j < 10; ++j) m = fmaxf(m, cc[j]);
          float den = 0.f;
          #pragma unroll
          for (int j = 0; j < 10; ++j) { cc[j] = __expf(cc[j] - m); den += cc[j]; }
          const float rd = __builtin_amdgcn_rcpf(den);
          #pragma unroll
          for (int j = 0; j < 10; ++j) ccl[(j * 16 + i) * 17 + b] = cc[j] * rd;
        }
        __syncthreads();
      }

      // phase B: s[b,d] += (c*x) @ Ws, K=128
      floatx4 acc = {0.f, 0.f, 0.f, 0.f};
      #pragma unroll
      for (int kt = 0; kt < 4; ++kt) {
        const int il = kt * 4 + quad;
        const uint4 xq = xtq[il * 17 + col];
        const uint4 wf = wsf[((size_t)wave * 288 + (by << 2) + kt) * 64 + lane];
        const float c = (round > 0) ? ccl[(wave * 16 + il) * 17 + col] : 0.1f;
        short8 af;
        unsigned int* aq = (unsigned int*)&af;
        aq[0] = pack_trunc(bf_lo(xq.x) * c, bf_hi(xq.x) * c);
        aq[1] = pack_trunc(bf_lo(xq.y) * c, bf_hi(xq.y) * c);
        aq[2] = pack_trunc(bf_lo(xq.z) * c, bf_hi(xq.z) * c);
        aq[3] = pack_trunc(bf_lo(xq.w) * c, bf_hi(xq.w) * c);
        u4s8 bw; bw.u = wf;
        acc = __builtin_amdgcn_mfma_f32_16x16x32_bf16(af, bw.s, acc, 0, 0, 0);
      }
      float* sp = s_part + ((((size_t)bx * 10 + wave) * 16 + quad * 4) * 72 + by) * 16 + col;
      #pragma unroll
      for (int r = 0; r < 4; ++r) sp[(size_t)r * 72 * 16] = acc[r];
    }

    grid.sync();   // all s_part partials visible

    // ---------------- squash: one wave per (b,j) -------------------------
    for (int bj = blk * 10 + wave; bj < B_N * J_N; bj += nblk * 10) {
      const int b = bj / 10, j = bj - b * 10;
      const int btile = b >> 4, brem = b & 15;
      const float* sbase = s_part + (((size_t)btile * 10 + j) * 16 + brem) * 1152;
      float acc = 0.f;
      #pragma unroll
      for (int q = 0; q < 18; ++q) acc += sbase[q * 64 + lane];
      acc += __shfl_xor(acc, 16, 64);
      acc += __shfl_xor(acc, 32, 64);
      const float s = acc;
      float sq = s * s;
      sq += __shfl_xor(sq, 1, 16);
      sq += __shfl_xor(sq, 2, 16);
      sq += __shfl_xor(sq, 4, 16);
      sq += __shfl_xor(sq, 8, 16);
      const float coef = (sq / (1.f + sq)) * rsqrtf(sq + 1e-7f);
      const float v = coef * s;
      if (round < 2) {
        const float vprev = (lane < 16) ? vsum[bj * 16 + lane] : 0.f;
        const float vt = vprev + v;
        const float vtn = __shfl_down(vt, 1, 64);
        if (lane < 16) {
          vsum[bj * 16 + lane] = vt;
          if (!(lane & 1))
            vsbf_u[bj * 8 + (lane >> 1)] = pack_rne(vt, vtn);
        }
      } else if (lane < 16) {
        out[bj * 16 + lane] = v;
      }
    }

    if (round < 2) grid.sync();   // vsbf visible before next round's phase A
  }
}

extern "C" void kernel_launch(void* const* d_in, const int* in_sizes, int n_in,
                              void* d_out, int out_size, void* d_ws, size_t ws_size,
                              hipStream_t stream)
{
  const float* x_p = (const float*)d_in[0];   // [256][1152][8] fp32
  const float* W_p = (const float*)d_in[1];   // [10][1152][16][8] fp32

  // ws: wsf 2.95M | wcc2 2.95M | s_part 11.8M | vsum 164K | vsbf 82K (~18 MB)
  uint4* wsf   = (uint4*)d_ws;
  uint4* wcc2  = wsf + 184320;
  float* s_prt = (float*)(wcc2 + 184320);             // 2949120 f
  float* vsum  = s_prt + 2949120;                     // 40960 f
  unsigned int* vsbf_u = (unsigned int*)(vsum + 40960);
  float* out_p = (float*)d_out;

  // Cooperative grid: occupancy-derived so the co-residency validation
  // can't fail. (640,5) => <=96 VGPR => 2 blocks/CU => 512 expected.
  static int s_grid = 0;
  if (s_grid == 0) {
    int occ = 0;
    hipError_t err = hipOccupancyMaxActiveBlocksPerMultiprocessor(
        &occ, (const void*)caps_fused, 640, 0);
    if (err != hipSuccess || occ < 1) occ = 1;
    long g = (long)occ * 256;
    if (g > 512) g = 512;                   // >512 can't help (1152 vblocks)
    s_grid = (int)g;
  }

  void* args[] = {(void*)&x_p, (void*)&W_p, (void*)&wsf, (void*)&wcc2,
                  (void*)&s_prt, (void*)&vsum, (void*)&vsbf_u, (void*)&out_p};
  hipLaunchCooperativeKernel((const void*)caps_fused, dim3(s_grid), dim3(640),
                             args, 0, stream);
}